// Round 11
// baseline (283.768 us; speedup 1.0000x reference)
//
#include <hip/hip_runtime.h>

// MultiHeadedAttention: B=4, S=2048, H=16, D_K=64, D_MODEL=1024
// Pipeline: [cvt_pre] -> [gemm_qkv] -> [flash attn] -> [gemm_out]
// ws layout:
//  base (64 MiB):  q_ws@0  k_ws@16M  vT@32M  o_ws@48M      (bf16)
//  big (+56 MiB):  xq_bf@64M xk_bf@80M xv_bf@96M wbf@112M  (needs ws>=120MiB)
//  small fallback: wbf3 @48M (aliases o_ws; dead before attn writes o_ws)

#define DMODEL 1024
#define SLEN 2048
#define NHEAD 16
#define LOG2E 1.44269504088896340736f

typedef __attribute__((ext_vector_type(4))) float f32x4;
typedef __attribute__((ext_vector_type(8))) short bf16x8;
typedef __attribute__((ext_vector_type(4))) int i32x4;
typedef __attribute__((ext_vector_type(2))) int i32x2;

__device__ __forceinline__ unsigned short f2bf(float f) {
  __bf16 h = (__bf16)f;
  union { __bf16 h; unsigned short u; } cv; cv.h = h; return cv.u;
}
__device__ __forceinline__ unsigned pk(float a, float b) {
  return (unsigned)f2bf(a) | ((unsigned)f2bf(b) << 16);
}
// single-instruction hardware exp2 (TRANS pipe); plain exp2f() cost attn 2x in R4.
__device__ __forceinline__ float fexp2(float x) {
  float r;
  asm("v_exp_f32 %0, %1" : "=v"(r) : "v"(x));
  return r;
}
__device__ __forceinline__ f32x4 zero4() {
  f32x4 z; z[0] = 0.f; z[1] = 0.f; z[2] = 0.f; z[3] = 0.f; return z;
}
// async global->LDS, 16B per lane; lds dest wave-uniform base + lane*16
__device__ __forceinline__ void gload16(const void* g, void* l) {
  __builtin_amdgcn_global_load_lds(
      (const __attribute__((address_space(1))) unsigned int*)(uintptr_t)g,
      (__attribute__((address_space(3))) unsigned int*)(uintptr_t)l, 16, 0, 0);
}

// ---------------------------------------------------------------------------
// Prepass: fp32 -> bf16. full=1: X(q,k,v) -> xbf[3][8M], W(q,k,v,o) -> wbf[4][1M].
// full=0: W(q,k,v) -> wbf[3][1M] only. 8 elems per chunk, grid-stride.
// ---------------------------------------------------------------------------
__global__ __launch_bounds__(256)
void cvt_pre(const float* __restrict__ xq, const float* __restrict__ xk,
             const float* __restrict__ xv,
             const float* __restrict__ Wq, const float* __restrict__ Wk,
             const float* __restrict__ Wv, const float* __restrict__ Wo,
             unsigned short* __restrict__ xbf, unsigned short* __restrict__ wbf,
             int full)
{
  const long nchunk = full ? 3670016L : 393216L;
  const long stride = (long)gridDim.x * blockDim.x;
  for (long c = (long)blockIdx.x * blockDim.x + threadIdx.x; c < nchunk; c += stride) {
    const float* src; unsigned short* dst; long off;
    if (full) {
      if (c < 3145728L) {           // X part: 3 x 2^20 chunks
        const int i = (int)(c >> 20);
        off = (c & 1048575L) * 8;
        src = (i == 0) ? xq : (i == 1) ? xk : xv;
        dst = xbf + (size_t)i * 8388608;
      } else {                      // W part: 4 x 2^17 chunks
        const long d = c - 3145728L;
        const int j = (int)(d >> 17);
        off = (d & 131071L) * 8;
        src = (j == 0) ? Wq : (j == 1) ? Wk : (j == 2) ? Wv : Wo;
        dst = wbf + (size_t)j * 1048576;
      }
    } else {                        // W3 only
      const int j = (int)(c >> 17);
      off = (c & 131071L) * 8;
      src = (j == 0) ? Wq : (j == 1) ? Wk : Wv;
      dst = wbf + (size_t)j * 1048576;
    }
    const float4 a = *(const float4*)(src + off);
    const float4 b = *(const float4*)(src + off + 4);
    i32x4 o;
    o[0] = (int)pk(a.x, a.y); o[1] = (int)pk(a.z, a.w);
    o[2] = (int)pk(b.x, b.y); o[3] = (int)pk(b.z, b.w);
    *(i32x4*)(dst + off) = o;
  }
}

// ---------------------------------------------------------------------------
// QKV projection. 128x128 tile, BK=32, 4 waves. B always DMA from wbf (bf16).
// ADMA=1: A also DMA from xbf -> zero staging VALU; linear [128][64B] LDS,
// conflict-free, no swizzle. ADMA=0: reg-staged fallback.  (unchanged R9)
// ---------------------------------------------------------------------------
template <bool ADMA>
__global__ __launch_bounds__(256)
void gemm_qkv_t(const float* __restrict__ xq, const float* __restrict__ xk,
                const float* __restrict__ xv,
                const unsigned short* __restrict__ xbf,
                const unsigned short* __restrict__ wbf,
                const float* __restrict__ bq, const float* __restrict__ bk,
                const float* __restrict__ bv,
                unsigned short* __restrict__ qw, unsigned short* __restrict__ kw,
                unsigned short* __restrict__ vw)
{
  const int bid = blockIdx.x;
  const int wg = (bid & 7) * 192 + (bid >> 3);   // 1536 = 8 * 192 bijective
  const int z = wg >> 9;
  const int r = wg & 511;
  const int m0 = (r >> 3) * 128;
  const int n0 = (r & 7) * 128;

  const float* __restrict__ X = (z == 0) ? xq : (z == 1) ? xk : xv;
  const unsigned short* __restrict__ Xb = xbf + (size_t)z * 8388608;
  const unsigned short* __restrict__ Wb = wbf + (size_t)z * 1048576;
  const float* __restrict__ bias = (z == 0) ? bq : (z == 1) ? bk : bv;
  const float scale = (z == 0) ? 0.125f * LOG2E : 1.0f;

  const int tid = threadIdx.x;
  const int lane = tid & 63, wid = tid >> 6;
  const int l15 = lane & 15, g = lane >> 4;
  const int wr = wid >> 1, wc = wid & 1;

  __shared__ __align__(16) char LDS[32768];
  unsigned short* TT = (unsigned short*)LDS;     // epilogue overlay [64][136]

  auto dmaB = [&](int kt2, int bufsel) {
    char* dst = LDS + 16384 + bufsel * 8192;
#pragma unroll
    for (int q = 0; q < 2; ++q) {
      const int r0 = wid * 32 + q * 16;
      const unsigned short* src = Wb + (size_t)(n0 + r0 + (lane >> 2)) * 1024
                                     + kt2 * 32 + (lane & 3) * 8;
      gload16(src, dst + r0 * 64);
    }
  };
  auto dmaA = [&](int kt2, int bufsel) {
    char* dst = LDS + bufsel * 8192;
#pragma unroll
    for (int q = 0; q < 2; ++q) {
      const int r0 = wid * 32 + q * 16;
      const unsigned short* src = Xb + (size_t)(m0 + r0 + (lane >> 2)) * 1024
                                     + kt2 * 32 + (lane & 3) * 8;
      gload16(src, dst + r0 * 64);
    }
  };

  // ---- A reg-staging fallback (ADMA=0) ----
  const int srow = tid >> 1, sh = tid & 1;
  const float* __restrict__ Ag = X + (size_t)(m0 + srow) * DMODEL + sh * 16;
  const unsigned sw0 = (unsigned)(srow * 64) + (((unsigned)(sh * 2))     ^ ((unsigned)((srow >> 1) & 3))) * 16;
  const unsigned sw1 = (unsigned)(srow * 64) + (((unsigned)(sh * 2 + 1)) ^ ((unsigned)((srow >> 1) & 3))) * 16;
  f32x4 ar4[4];
  auto loadA = [&](int kt2) {
    const float* p = Ag + kt2 * 32;
#pragma unroll
    for (int j = 0; j < 4; ++j) ar4[j] = *(const f32x4*)(p + j * 4);
  };
  auto packA = [&](int bufsel) {
    char* Ab = LDS + bufsel * 8192;
    i32x4 wv0, wv1;
    wv0[0] = (int)pk(ar4[0][0], ar4[0][1]); wv0[1] = (int)pk(ar4[0][2], ar4[0][3]);
    wv0[2] = (int)pk(ar4[1][0], ar4[1][1]); wv0[3] = (int)pk(ar4[1][2], ar4[1][3]);
    wv1[0] = (int)pk(ar4[2][0], ar4[2][1]); wv1[1] = (int)pk(ar4[2][2], ar4[2][3]);
    wv1[2] = (int)pk(ar4[3][0], ar4[3][1]); wv1[3] = (int)pk(ar4[3][2], ar4[3][3]);
    *(i32x4*)(Ab + sw0) = wv0;
    *(i32x4*)(Ab + sw1) = wv1;
  };

  f32x4 acc[4][4];
#pragma unroll
  for (int i = 0; i < 4; ++i)
#pragma unroll
    for (int j = 0; j < 4; ++j) acc[i][j] = zero4();

  if (ADMA) {
    dmaA(0, 0);
  } else {
    loadA(0); packA(0); loadA(1);
  }
  dmaB(0, 0);
  __syncthreads();

  for (int kt = 0; kt < 32; ++kt) {
    const int cur = kt & 1;
    if (kt + 1 < 32) {
      dmaB(kt + 1, cur ^ 1);
      if (ADMA) dmaA(kt + 1, cur ^ 1);
      else      packA(cur ^ 1);
    }
    if (!ADMA && kt + 2 < 32) loadA(kt + 2);

    const char* Ab = LDS + cur * 8192;
    const char* Bb = LDS + 16384 + cur * 8192;
    bf16x8 afr[4], bfr[4];
#pragma unroll
    for (int i = 0; i < 4; ++i) {
      const int ra = wr * 64 + i * 16 + l15;
      const unsigned ab = ADMA ? (unsigned)(g * 16)
                               : ((unsigned)(g ^ ((ra >> 1) & 3)) * 16);
      afr[i] = *(const bf16x8*)(Ab + ra * 64 + ab);
      const int rb = wc * 64 + i * 16 + l15;
      bfr[i] = *(const bf16x8*)(Bb + rb * 64 + g * 16);
    }
#pragma unroll
    for (int mi = 0; mi < 4; ++mi)
#pragma unroll
      for (int ni = 0; ni < 4; ++ni)
        acc[mi][ni] = __builtin_amdgcn_mfma_f32_16x16x32_bf16(
            afr[mi], bfr[ni], acc[mi][ni], 0, 0, 0);

    if (kt + 1 < 32) __syncthreads();
  }

  float bv4[4];
#pragma unroll
  for (int ni = 0; ni < 4; ++ni) bv4[ni] = bias[n0 + wc * 64 + ni * 16 + l15];

  if (z == 2) {
    const int bb = m0 >> 11, s0 = m0 & 2047;
#pragma unroll
    for (int p = 0; p < 2; ++p) {
      __syncthreads();
      if (wc == p) {
#pragma unroll
        for (int mi = 0; mi < 4; ++mi)
#pragma unroll
          for (int ni = 0; ni < 4; ++ni)
#pragma unroll
            for (int rr2 = 0; rr2 < 4; ++rr2)
              TT[(ni * 16 + l15) * 136 + wr * 64 + mi * 16 + 4 * g + rr2] =
                  f2bf(acc[mi][ni][rr2] + bv4[ni]);
      }
      __syncthreads();
      const int rr = tid >> 2, cc = (tid & 3) * 32;
      unsigned short* dp = vw + ((size_t)(bb * 1024 + n0 + p * 64 + rr)) * 2048 + s0 + cc;
      const unsigned short* sp = &TT[rr * 136 + cc];
#pragma unroll
      for (int j = 0; j < 4; ++j)
        *(i32x4*)(void*)(dp + j * 8) = *(const i32x4*)(const void*)(sp + j * 8);
    }
    return;
  }

  unsigned short* __restrict__ dst = (z == 0) ? qw : kw;
#pragma unroll
  for (int mi = 0; mi < 4; ++mi) {
#pragma unroll
    for (int ni = 0; ni < 4; ++ni) {
      const int n = n0 + wc * 64 + ni * 16 + l15;
      const int h = n >> 6, d = n & 63;
#pragma unroll
      for (int rr2 = 0; rr2 < 4; ++rr2) {
        const int m = m0 + wr * 64 + mi * 16 + 4 * g + rr2;
        const int b = m >> 11, s = m & 2047;
        const float val = (acc[mi][ni][rr2] + bv4[ni]) * scale;
        dst[((size_t)(b * NHEAD + h) * SLEN + s) * 64 + d] = f2bf(val);
      }
    }
  }
}

// ---------------------------------------------------------------------------
// Flash attention. R11: KVBLK 32, QBLK 64 (4 waves x 16 q, qi loop removed).
// LDS 20480 (Kb 8K dbuf + Vb 8K dbuf + Pl 4K) -> exactly 8 blocks/CU
// (8 x 20480 = 160 KiB) = 32 waves/CU at VGPR<=64: 2x the TLP of R10
// (which was VALU+latency bound at 55% VALUBusy / 23% idle).
// Swizzle keys re-derived: K rows 128B -> l15&7; V/P rows 64B -> l15&3.
// ---------------------------------------------------------------------------
__global__ __launch_bounds__(256, 8)
void attn(const unsigned short* __restrict__ q_ws,
          const unsigned short* __restrict__ k_ws,
          const unsigned short* __restrict__ vT,
          const int* __restrict__ mask,
          unsigned short* __restrict__ o_ws)
{
  const int bh = blockIdx.x;            // 0..63
  const int qt = blockIdx.y;            // 0..31
  const int b = bh >> 4, h = bh & 15;
  const int tid = threadIdx.x, w = tid >> 6, lane = tid & 63;
  const int l15 = lane & 15, g = lane >> 4;

  __shared__ __align__(16) unsigned short Kb[2][32 * 64];   // 8 KB  [kv][d]
  __shared__ __align__(16) unsigned short Vb[2][64 * 32];   // 8 KB  [d][kv]
  __shared__ __align__(16) unsigned short Pl[4][16 * 32];   // 4 KB  per-wave [q][kv]

  const int* __restrict__ maskp = mask + b * SLEN;
  const size_t head = (size_t)bh * SLEN;

  // K staging: 32 rows x 128B; wave w rows w*8..+7
  const int r8 = lane >> 3, c8 = lane & 7;
  const int kswz = (c8 ^ r8) * 16;               // source chunk pre-swizzle
  // V staging: 64 rows x 64B; wave w rows w*16..+15
  const int r4 = lane >> 2, c4 = lane & 3;
  const int vswz = (c4 ^ (r4 & 3)) * 16;

  const unsigned pswzK = (unsigned)((l15 & 7) << 4);   // Kb reads (128B rows)
  const unsigned pswzV = (unsigned)((l15 & 3) << 4);   // Vb reads (64B rows)

  const int qbase = qt * 64 + w * 16;
  bf16x8 qf0, qf1;
  {
    const unsigned short* qp = q_ws + (head + qbase + l15) * 64;
    qf0 = *(const bf16x8*)(qp + g * 8);
    qf1 = *(const bf16x8*)(qp + 32 + g * 8);
  }

  auto stage = [&](int kt2, int bufi) {
    const int kr = w * 8 + r8;
    const char* gk = (const char*)(k_ws + (head + kt2 * 32 + kr) * 64) + kswz;
    gload16(gk, &Kb[bufi][(w * 8) * 64]);
    const int vr = w * 16 + r4;
    const char* gv = (const char*)(vT + ((size_t)(bh * 64 + vr)) * SLEN + kt2 * 32) + vswz;
    gload16(gv, &Vb[bufi][(w * 16) * 32]);
  };

  stage(0, 0);
  __syncthreads();

  float m_run = -1e30f, l_run = 0.f;
  f32x4 of[4];
#pragma unroll
  for (int n = 0; n < 4; ++n) of[n] = zero4();

  unsigned short* Pw = (unsigned short*)Pl[w];
  int cur = 0;

  for (int kt = 0; kt < 64; ++kt) {
    const int kv0 = kt * 32;
    // mask bias: 2x int4 from L2-resident mask (no LDS)
    f32x4 mv[2];
#pragma unroll
    for (int s = 0; s < 2; ++s) {
      const int4 mm = *(const int4*)(maskp + kv0 + s * 16 + g * 4);
      mv[s][0] = mm.x ? 0.f : -1e9f;
      mv[s][1] = mm.y ? 0.f : -1e9f;
      mv[s][2] = mm.z ? 0.f : -1e9f;
      mv[s][3] = mm.w ? 0.f : -1e9f;
    }
    if (kt + 1 < 64) stage(kt + 1, cur ^ 1);
    const char* Kc = (const char*)Kb[cur];
    const char* Vc = (const char*)Vb[cur];

    // ---- S^T = K @ Q^T (mask as C-init) ----
    f32x4 sac[2];
    __builtin_amdgcn_s_setprio(1);
#pragma unroll
    for (int s = 0; s < 2; ++s) {
      const char* kr = Kc + (s * 16 + l15) * 128;
      const bf16x8 kf0 = *(const bf16x8*)(kr + ((unsigned)(g * 16) ^ pswzK));
      const bf16x8 kf1 = *(const bf16x8*)(kr + ((unsigned)(64 + g * 16) ^ pswzK));
      f32x4 zt = mv[s];
      zt = __builtin_amdgcn_mfma_f32_16x16x32_bf16(kf0, qf0, zt, 0, 0, 0);
      sac[s] = __builtin_amdgcn_mfma_f32_16x16x32_bf16(kf1, qf1, zt, 0, 0, 0);
    }
    __builtin_amdgcn_s_setprio(0);

    // ---- online softmax (exp2 domain), defer-max THR=8 ----
    float tmax = -3.0e38f;
#pragma unroll
    for (int s = 0; s < 2; ++s)
#pragma unroll
      for (int rr = 0; rr < 4; ++rr) tmax = fmaxf(tmax, sac[s][rr]);
    tmax = fmaxf(tmax, __shfl_xor(tmax, 16));
    tmax = fmaxf(tmax, __shfl_xor(tmax, 32));
    if (!__all(tmax <= m_run + 8.f)) {
      const float mnew = fmaxf(m_run, tmax);
      const float alpha = fexp2(m_run - mnew);
      float af[4];
#pragma unroll
      for (int rr = 0; rr < 4; ++rr) af[rr] = __shfl(alpha, g * 4 + rr);
#pragma unroll
      for (int n = 0; n < 4; ++n)
#pragma unroll
        for (int rr = 0; rr < 4; ++rr) of[n][rr] *= af[rr];
      l_run *= alpha;
      m_run = mnew;
    }
    float psum = 0.f;
    unsigned pr[2][2];
#pragma unroll
    for (int s = 0; s < 2; ++s) {
      const float p0 = fexp2(sac[s][0] - m_run);
      const float p1 = fexp2(sac[s][1] - m_run);
      const float p2 = fexp2(sac[s][2] - m_run);
      const float p3 = fexp2(sac[s][3] - m_run);
      psum += (p0 + p1) + (p2 + p3);
      pr[s][0] = pk(p0, p1); pr[s][1] = pk(p2, p3);
    }
    l_run += psum;
#pragma unroll
    for (int s = 0; s < 2; ++s) {
      i32x2 wv; wv[0] = (int)pr[s][0]; wv[1] = (int)pr[s][1];
      // P[q=l15][kv=16s+4g..+3]: byte 32s+8g, chunk (2s+(g>>1)) ^ (l15&3)
      *(i32x2*)(void*)((char*)Pw + l15 * 64 + (((unsigned)(s * 32 + g * 8)) ^ pswzV)) = wv;
    }

    // ---- O += P @ V (single K=32 step) ----
    const bf16x8 pa = *(const bf16x8*)(const void*)(
        (const char*)Pw + l15 * 64 + (((unsigned)(g * 16)) ^ pswzV));
    __builtin_amdgcn_s_setprio(1);
#pragma unroll
    for (int n = 0; n < 4; ++n) {
      const bf16x8 vf = *(const bf16x8*)(
          Vc + (n * 16 + l15) * 64 + (((unsigned)(g * 16)) ^ pswzV));
      of[n] = __builtin_amdgcn_mfma_f32_16x16x32_bf16(pa, vf, of[n], 0, 0, 0);
    }
    __builtin_amdgcn_s_setprio(0);
    __syncthreads();
    cur ^= 1;
  }

  // ---- finalize ----
  float lt = l_run;
  lt += __shfl_xor(lt, 16);
  lt += __shfl_xor(lt, 32);
  float inv[4];
#pragma unroll
  for (int rr = 0; rr < 4; ++rr) inv[rr] = 1.f / __shfl(lt, g * 4 + rr);
  const int qrow0 = qt * 64 + w * 16;
#pragma unroll
  for (int n = 0; n < 4; ++n) {
    const int d = h * 64 + n * 16 + l15;
#pragma unroll
    for (int rr = 0; rr < 4; ++rr) {
      const int sr = qrow0 + 4 * g + rr;
      o_ws[((size_t)b * SLEN + sr) * DMODEL + d] = f2bf(of[n][rr] * inv[rr]);
    }
  }
}

// ---------------------------------------------------------------------------
// Output projection. DMA=1: A (o_ws bf16) + B (Wo_bf) both via gload16,
// linear LDS. DMA=0: reg-staged fallback.  (unchanged R9)
// ---------------------------------------------------------------------------
template <bool DMA>
__global__ __launch_bounds__(256)
void gemm_out_t(const unsigned short* __restrict__ ow,
                const unsigned short* __restrict__ wob,
                const float* __restrict__ Wo, const float* __restrict__ bo,
                float* __restrict__ out)
{
  const int bid = blockIdx.x;                      // 512 = 8 * 64
  const int wg = (bid & 7) * 64 + (bid >> 3);
  const int m0 = (wg >> 3) * 128;
  const int n0 = (wg & 7) * 128;

  const int tid = threadIdx.x;
  const int lane = tid & 63, wid = tid >> 6;
  const int l15 = lane & 15, g = lane >> 4;
  const int wr = wid >> 1, wc = wid & 1;

  __shared__ __align__(16) char LDS[32768];

  auto dmaA = [&](int kt2, int bufsel) {
    char* dst = LDS + bufsel * 8192;
#pragma unroll
    for (int q = 0; q < 2; ++q) {
      const int r0 = wid * 32 + q * 16;
      const unsigned short* src = ow + (size_t)(m0 + r0 + (lane >> 2)) * 1024
                                     + kt2 * 32 + (lane & 3) * 8;
      gload16(src, dst + r0 * 64);
    }
  };
  auto dmaB = [&](int kt2, int bufsel) {
    char* dst = LDS + 16384 + bufsel * 8192;
#pragma unroll
    for (int q = 0; q < 2; ++q) {
      const int r0 = wid * 32 + q * 16;
      const unsigned short* src = wob + (size_t)(n0 + r0 + (lane >> 2)) * 1024
                                      + kt2 * 32 + (lane & 3) * 8;
      gload16(src, dst + r0 * 64);
    }
  };

  const int srow = tid >> 1, sh = tid & 1;
  const unsigned short* __restrict__ Ag = ow + (size_t)(m0 + srow) * DMODEL + sh * 16;
  const float* __restrict__ Bg = Wo + (size_t)(n0 + srow) * DMODEL + sh * 16;
  const unsigned sw0 = (unsigned)(srow * 64) + (((unsigned)(sh * 2))     ^ ((unsigned)((srow >> 1) & 3))) * 16;
  const unsigned sw1 = (unsigned)(srow * 64) + (((unsigned)(sh * 2 + 1)) ^ ((unsigned)((srow >> 1) & 3))) * 16;
  i32x4 ar2[2];
  f32x4 br4[4];
  auto loadA = [&](int kt2) {
    const unsigned short* p = Ag + kt2 * 32;
    ar2[0] = *(const i32x4*)(p);
    ar2[1] = *(const i32x4*)(p + 8);
  };
  auto loadB = [&](int kt2) {
    const float* p = Bg + kt2 * 32;
#pragma unroll
    for (int j = 0; j < 4; ++j) br4[j] = *(const f32x4*)(p + j * 4);
  };
  auto packA = [&](int bufsel) {
    char* Ab = LDS + bufsel * 8192;
    *(i32x4*)(Ab + sw0) = ar2[0];
    *(i32x4*)(Ab + sw1) = ar2[1];
  };
  auto packB = [&](int bufsel) {
    char* Bb = LDS + 16384 + bufsel * 8192;
    i32x4 wv0, wv1;
    wv0[0] = (int)pk(br4[0][0], br4[0][1]); wv0[1] = (int)pk(br4[0][2], br4[0][3]);
    wv0[2] = (int)pk(br4[1][0], br4[1][1]); wv0[3] = (int)pk(br4[1][2], br4[1][3]);
    wv1[0] = (int)pk(br4[2][0], br4[2][1]); wv1[1] = (int)pk(br4[2][2], br4[2][3]);
    wv1[2] = (int)pk(br4[3][0], br4[3][1]); wv1[3] = (int)pk(br4[3][2], br4[3][3]);
    *(i32x4*)(Bb + sw0) = wv0;
    *(i32x4*)(Bb + sw1) = wv1;
  };

  f32x4 acc[4][4];
#pragma unroll
  for (int i = 0; i < 4; ++i)
#pragma unroll
    for (int j = 0; j < 4; ++j) acc[i][j] = zero4();

  if (DMA) {
    dmaA(0, 0); dmaB(0, 0);
  } else {
    loadA(0); loadB(0);
    packA(0); packB(0);
    loadA(1); loadB(1);
  }
  __syncthreads();

  for (int kt = 0; kt < 32; ++kt) {
    const int cur = kt & 1;
    if (kt + 1 < 32) {
      if (DMA) { dmaA(kt + 1, cur ^ 1); dmaB(kt + 1, cur ^ 1); }
      else     { packA(cur ^ 1); packB(cur ^ 1); }
    }
    if (!DMA && kt + 2 < 32) { loadA(kt + 2); loadB(kt + 2); }

    const char* Ab = LDS + cur * 8192;
    const char* Bb = LDS + 16384 + cur * 8192;
    bf16x8 afr[4], bfr[4];
#pragma unroll
    for (int i = 0; i < 4; ++i) {
      const int ra = wr * 64 + i * 16 + l15;
      const unsigned ab = DMA ? (unsigned)(g * 16)
                              : ((unsigned)(g ^ ((ra >> 1) & 3)) * 16);
      afr[i] = *(const bf16x8*)(Ab + ra * 64 + ab);
      const int rb = wc * 64 + i * 16 + l15;
      const unsigned bb2 = DMA ? (unsigned)(g * 16)
                               : ((unsigned)(g ^ ((rb >> 1) & 3)) * 16);
      bfr[i] = *(const bf16x8*)(Bb + rb * 64 + bb2);
    }
#pragma unroll
    for (int mi = 0; mi < 4; ++mi)
#pragma unroll
      for (int ni = 0; ni < 4; ++ni)
        acc[mi][ni] = __builtin_amdgcn_mfma_f32_16x16x32_bf16(
            afr[mi], bfr[ni], acc[mi][ni], 0, 0, 0);

    if (kt + 1 < 32) __syncthreads();
  }

  float bv4[4];
#pragma unroll
  for (int ni = 0; ni < 4; ++ni) bv4[ni] = bo[n0 + wc * 64 + ni * 16 + l15];
#pragma unroll
  for (int mi = 0; mi < 4; ++mi) {
#pragma unroll
    for (int ni = 0; ni < 4; ++ni) {
      const int n = n0 + wc * 64 + ni * 16 + l15;
#pragma unroll
      for (int rr = 0; rr < 4; ++rr) {
        const int m = m0 + wr * 64 + mi * 16 + 4 * g + rr;
        out[(size_t)m * DMODEL + n] = acc[mi][ni][rr] + bv4[ni];
      }
    }
  }
}

// ---------------------------------------------------------------------------
extern "C" void kernel_launch(void* const* d_in, const int* in_sizes, int n_in,
                              void* d_out, int out_size, void* d_ws, size_t ws_size,
                              hipStream_t stream) {
  const float* query = (const float*)d_in[0];
  const float* key_  = (const float*)d_in[1];
  const float* value = (const float*)d_in[2];
  const int*   mask  = (const int*)d_in[3];
  const float* Wq = (const float*)d_in[4];
  const float* bq = (const float*)d_in[5];
  const float* Wk = (const float*)d_in[6];
  const float* bk = (const float*)d_in[7];
  const float* Wv = (const float*)d_in[8];
  const float* bv = (const float*)d_in[9];
  const float* Wo = (const float*)d_in[10];
  const float* bo = (const float*)d_in[11];
  float* out = (float*)d_out;

  const size_t MiB = 1048576;
  char* ws = (char*)d_ws;
  unsigned short* q_ws = (unsigned short*)(ws);
  unsigned short* k_ws = (unsigned short*)(ws + 16 * MiB);
  unsigned short* vT   = (unsigned short*)(ws + 32 * MiB);
  unsigned short* o_ws = (unsigned short*)(ws + 48 * MiB);

  const bool big = ws_size >= 120 * MiB;
  unsigned short* xbf = big ? (unsigned short*)(ws + 64 * MiB) : (unsigned short*)0;
  unsigned short* wbf = big ? (unsigned short*)(ws + 112 * MiB)
                            : (unsigned short*)(ws + 48 * MiB);  // aliases o_ws (dead before attn)

  cvt_pre<<<dim3(2048), 256, 0, stream>>>(query, key_, value, Wq, Wk, Wv, Wo,
                                          xbf, wbf, big ? 1 : 0);
  if (big)
    gemm_qkv_t<true><<<dim3(1536), 256, 0, stream>>>(query, key_, value, xbf, wbf,
                                                     bq, bk, bv, q_ws, k_ws, vT);
  else
    gemm_qkv_t<false><<<dim3(1536), 256, 0, stream>>>(query, key_, value, xbf, wbf,
                                                      bq, bk, bv, q_ws, k_ws, vT);
  attn<<<dim3(64, 32), 256, 0, stream>>>(q_ws, k_ws, vT, mask, o_ws);
  if (big)
    gemm_out_t<true><<<dim3(512), 256, 0, stream>>>(o_ws, wbf + (size_t)3 * 1048576,
                                                    Wo, bo, out);
  else
    gemm_out_t<false><<<dim3(512), 256, 0, stream>>>(o_ws, (const unsigned short*)0,
                                                     Wo, bo, out);
}

// Round 12
// 259.006 us; speedup vs baseline: 1.0956x; 1.0956x over previous
//
#include <hip/hip_runtime.h>

// MultiHeadedAttention: B=4, S=2048, H=16, D_K=64, D_MODEL=1024
// Pipeline: [cvt_pre] -> [gemm_qkv] -> [flash attn] -> [gemm_out]
// ws layout:
//  base (64 MiB):  q_ws@0  k_ws@16M  vT@32M  o_ws@48M      (bf16)
//  big (+56 MiB):  xq_bf@64M xk_bf@80M xv_bf@96M wbf@112M  (needs ws>=120MiB)
//  small fallback: wbf3 @48M (aliases o_ws; dead before attn writes o_ws)

#define DMODEL 1024
#define SLEN 2048
#define NHEAD 16
#define LOG2E 1.44269504088896340736f

typedef __attribute__((ext_vector_type(4))) float f32x4;
typedef __attribute__((ext_vector_type(8))) short bf16x8;
typedef __attribute__((ext_vector_type(4))) int i32x4;
typedef __attribute__((ext_vector_type(2))) int i32x2;

__device__ __forceinline__ unsigned short f2bf(float f) {
  __bf16 h = (__bf16)f;
  union { __bf16 h; unsigned short u; } cv; cv.h = h; return cv.u;
}
__device__ __forceinline__ unsigned pk(float a, float b) {
  return (unsigned)f2bf(a) | ((unsigned)f2bf(b) << 16);
}
// single-instruction hardware exp2 (TRANS pipe); plain exp2f() cost attn 2x in R4.
__device__ __forceinline__ float fexp2(float x) {
  float r;
  asm("v_exp_f32 %0, %1" : "=v"(r) : "v"(x));
  return r;
}
__device__ __forceinline__ f32x4 zero4() {
  f32x4 z; z[0] = 0.f; z[1] = 0.f; z[2] = 0.f; z[3] = 0.f; return z;
}
// async global->LDS, 16B per lane; lds dest wave-uniform base + lane*16
__device__ __forceinline__ void gload16(const void* g, void* l) {
  __builtin_amdgcn_global_load_lds(
      (const __attribute__((address_space(1))) unsigned int*)(uintptr_t)g,
      (__attribute__((address_space(3))) unsigned int*)(uintptr_t)l, 16, 0, 0);
}

// ---------------------------------------------------------------------------
// Prepass: fp32 -> bf16. full=1: X(q,k,v) -> xbf[3][8M], W(q,k,v,o) -> wbf[4][1M].
// full=0: W(q,k,v) -> wbf[3][1M] only. 8 elems per chunk, grid-stride.
// ---------------------------------------------------------------------------
__global__ __launch_bounds__(256)
void cvt_pre(const float* __restrict__ xq, const float* __restrict__ xk,
             const float* __restrict__ xv,
             const float* __restrict__ Wq, const float* __restrict__ Wk,
             const float* __restrict__ Wv, const float* __restrict__ Wo,
             unsigned short* __restrict__ xbf, unsigned short* __restrict__ wbf,
             int full)
{
  const long nchunk = full ? 3670016L : 393216L;
  const long stride = (long)gridDim.x * blockDim.x;
  for (long c = (long)blockIdx.x * blockDim.x + threadIdx.x; c < nchunk; c += stride) {
    const float* src; unsigned short* dst; long off;
    if (full) {
      if (c < 3145728L) {           // X part: 3 x 2^20 chunks
        const int i = (int)(c >> 20);
        off = (c & 1048575L) * 8;
        src = (i == 0) ? xq : (i == 1) ? xk : xv;
        dst = xbf + (size_t)i * 8388608;
      } else {                      // W part: 4 x 2^17 chunks
        const long d = c - 3145728L;
        const int j = (int)(d >> 17);
        off = (d & 131071L) * 8;
        src = (j == 0) ? Wq : (j == 1) ? Wk : (j == 2) ? Wv : Wo;
        dst = wbf + (size_t)j * 1048576;
      }
    } else {                        // W3 only
      const int j = (int)(c >> 17);
      off = (c & 131071L) * 8;
      src = (j == 0) ? Wq : (j == 1) ? Wk : Wv;
      dst = wbf + (size_t)j * 1048576;
    }
    const float4 a = *(const float4*)(src + off);
    const float4 b = *(const float4*)(src + off + 4);
    i32x4 o;
    o[0] = (int)pk(a.x, a.y); o[1] = (int)pk(a.z, a.w);
    o[2] = (int)pk(b.x, b.y); o[3] = (int)pk(b.z, b.w);
    *(i32x4*)(dst + off) = o;
  }
}

// ---------------------------------------------------------------------------
// QKV projection. 128x128 tile, BK=32, 4 waves. B always DMA from wbf (bf16).
// ADMA=1: A also DMA from xbf -> zero staging VALU; linear [128][64B] LDS,
// conflict-free, no swizzle. ADMA=0: reg-staged fallback.  (unchanged R9)
// ---------------------------------------------------------------------------
template <bool ADMA>
__global__ __launch_bounds__(256)
void gemm_qkv_t(const float* __restrict__ xq, const float* __restrict__ xk,
                const float* __restrict__ xv,
                const unsigned short* __restrict__ xbf,
                const unsigned short* __restrict__ wbf,
                const float* __restrict__ bq, const float* __restrict__ bk,
                const float* __restrict__ bv,
                unsigned short* __restrict__ qw, unsigned short* __restrict__ kw,
                unsigned short* __restrict__ vw)
{
  const int bid = blockIdx.x;
  const int wg = (bid & 7) * 192 + (bid >> 3);   // 1536 = 8 * 192 bijective
  const int z = wg >> 9;
  const int r = wg & 511;
  const int m0 = (r >> 3) * 128;
  const int n0 = (r & 7) * 128;

  const float* __restrict__ X = (z == 0) ? xq : (z == 1) ? xk : xv;
  const unsigned short* __restrict__ Xb = xbf + (size_t)z * 8388608;
  const unsigned short* __restrict__ Wb = wbf + (size_t)z * 1048576;
  const float* __restrict__ bias = (z == 0) ? bq : (z == 1) ? bk : bv;
  const float scale = (z == 0) ? 0.125f * LOG2E : 1.0f;

  const int tid = threadIdx.x;
  const int lane = tid & 63, wid = tid >> 6;
  const int l15 = lane & 15, g = lane >> 4;
  const int wr = wid >> 1, wc = wid & 1;

  __shared__ __align__(16) char LDS[32768];
  unsigned short* TT = (unsigned short*)LDS;     // epilogue overlay [64][136]

  auto dmaB = [&](int kt2, int bufsel) {
    char* dst = LDS + 16384 + bufsel * 8192;
#pragma unroll
    for (int q = 0; q < 2; ++q) {
      const int r0 = wid * 32 + q * 16;
      const unsigned short* src = Wb + (size_t)(n0 + r0 + (lane >> 2)) * 1024
                                     + kt2 * 32 + (lane & 3) * 8;
      gload16(src, dst + r0 * 64);
    }
  };
  auto dmaA = [&](int kt2, int bufsel) {
    char* dst = LDS + bufsel * 8192;
#pragma unroll
    for (int q = 0; q < 2; ++q) {
      const int r0 = wid * 32 + q * 16;
      const unsigned short* src = Xb + (size_t)(m0 + r0 + (lane >> 2)) * 1024
                                     + kt2 * 32 + (lane & 3) * 8;
      gload16(src, dst + r0 * 64);
    }
  };

  // ---- A reg-staging fallback (ADMA=0) ----
  const int srow = tid >> 1, sh = tid & 1;
  const float* __restrict__ Ag = X + (size_t)(m0 + srow) * DMODEL + sh * 16;
  const unsigned sw0 = (unsigned)(srow * 64) + (((unsigned)(sh * 2))     ^ ((unsigned)((srow >> 1) & 3))) * 16;
  const unsigned sw1 = (unsigned)(srow * 64) + (((unsigned)(sh * 2 + 1)) ^ ((unsigned)((srow >> 1) & 3))) * 16;
  f32x4 ar4[4];
  auto loadA = [&](int kt2) {
    const float* p = Ag + kt2 * 32;
#pragma unroll
    for (int j = 0; j < 4; ++j) ar4[j] = *(const f32x4*)(p + j * 4);
  };
  auto packA = [&](int bufsel) {
    char* Ab = LDS + bufsel * 8192;
    i32x4 wv0, wv1;
    wv0[0] = (int)pk(ar4[0][0], ar4[0][1]); wv0[1] = (int)pk(ar4[0][2], ar4[0][3]);
    wv0[2] = (int)pk(ar4[1][0], ar4[1][1]); wv0[3] = (int)pk(ar4[1][2], ar4[1][3]);
    wv1[0] = (int)pk(ar4[2][0], ar4[2][1]); wv1[1] = (int)pk(ar4[2][2], ar4[2][3]);
    wv1[2] = (int)pk(ar4[3][0], ar4[3][1]); wv1[3] = (int)pk(ar4[3][2], ar4[3][3]);
    *(i32x4*)(Ab + sw0) = wv0;
    *(i32x4*)(Ab + sw1) = wv1;
  };

  f32x4 acc[4][4];
#pragma unroll
  for (int i = 0; i < 4; ++i)
#pragma unroll
    for (int j = 0; j < 4; ++j) acc[i][j] = zero4();

  if (ADMA) {
    dmaA(0, 0);
  } else {
    loadA(0); packA(0); loadA(1);
  }
  dmaB(0, 0);
  __syncthreads();

  for (int kt = 0; kt < 32; ++kt) {
    const int cur = kt & 1;
    if (kt + 1 < 32) {
      dmaB(kt + 1, cur ^ 1);
      if (ADMA) dmaA(kt + 1, cur ^ 1);
      else      packA(cur ^ 1);
    }
    if (!ADMA && kt + 2 < 32) loadA(kt + 2);

    const char* Ab = LDS + cur * 8192;
    const char* Bb = LDS + 16384 + cur * 8192;
    bf16x8 afr[4], bfr[4];
#pragma unroll
    for (int i = 0; i < 4; ++i) {
      const int ra = wr * 64 + i * 16 + l15;
      const unsigned ab = ADMA ? (unsigned)(g * 16)
                               : ((unsigned)(g ^ ((ra >> 1) & 3)) * 16);
      afr[i] = *(const bf16x8*)(Ab + ra * 64 + ab);
      const int rb = wc * 64 + i * 16 + l15;
      bfr[i] = *(const bf16x8*)(Bb + rb * 64 + g * 16);
    }
#pragma unroll
    for (int mi = 0; mi < 4; ++mi)
#pragma unroll
      for (int ni = 0; ni < 4; ++ni)
        acc[mi][ni] = __builtin_amdgcn_mfma_f32_16x16x32_bf16(
            afr[mi], bfr[ni], acc[mi][ni], 0, 0, 0);

    if (kt + 1 < 32) __syncthreads();
  }

  float bv4[4];
#pragma unroll
  for (int ni = 0; ni < 4; ++ni) bv4[ni] = bias[n0 + wc * 64 + ni * 16 + l15];

  if (z == 2) {
    const int bb = m0 >> 11, s0 = m0 & 2047;
#pragma unroll
    for (int p = 0; p < 2; ++p) {
      __syncthreads();
      if (wc == p) {
#pragma unroll
        for (int mi = 0; mi < 4; ++mi)
#pragma unroll
          for (int ni = 0; ni < 4; ++ni)
#pragma unroll
            for (int rr2 = 0; rr2 < 4; ++rr2)
              TT[(ni * 16 + l15) * 136 + wr * 64 + mi * 16 + 4 * g + rr2] =
                  f2bf(acc[mi][ni][rr2] + bv4[ni]);
      }
      __syncthreads();
      const int rr = tid >> 2, cc = (tid & 3) * 32;
      unsigned short* dp = vw + ((size_t)(bb * 1024 + n0 + p * 64 + rr)) * 2048 + s0 + cc;
      const unsigned short* sp = &TT[rr * 136 + cc];
#pragma unroll
      for (int j = 0; j < 4; ++j)
        *(i32x4*)(void*)(dp + j * 8) = *(const i32x4*)(const void*)(sp + j * 8);
    }
    return;
  }

  unsigned short* __restrict__ dst = (z == 0) ? qw : kw;
#pragma unroll
  for (int mi = 0; mi < 4; ++mi) {
#pragma unroll
    for (int ni = 0; ni < 4; ++ni) {
      const int n = n0 + wc * 64 + ni * 16 + l15;
      const int h = n >> 6, d = n & 63;
#pragma unroll
      for (int rr2 = 0; rr2 < 4; ++rr2) {
        const int m = m0 + wr * 64 + mi * 16 + 4 * g + rr2;
        const int b = m >> 11, s = m & 2047;
        const float val = (acc[mi][ni][rr2] + bv4[ni]) * scale;
        dst[((size_t)(b * NHEAD + h) * SLEN + s) * 64 + d] = f2bf(val);
      }
    }
  }
}

// ---------------------------------------------------------------------------
// Flash attention — EXACT R10 configuration (best measured: 134 us).
// QBLK 128 (4 waves x 32 q), KVBLK 64, LDS 40960 (4 blocks/CU), mask bias
// loaded per tile as int4 from L2-resident mask, setprio around MFMA
// clusters. R11's KVBLK-32 variant regressed (5.5x bank conflicts from the
// 64B-row swizzle + doubled per-tile fixed overhead) and was reverted.
// ---------------------------------------------------------------------------
__global__ __launch_bounds__(256, 3)
void attn(const unsigned short* __restrict__ q_ws,
          const unsigned short* __restrict__ k_ws,
          const unsigned short* __restrict__ vT,
          const int* __restrict__ mask,
          unsigned short* __restrict__ o_ws)
{
  const int bh = blockIdx.x;
  const int qt = blockIdx.y;
  const int b = bh >> 4, h = bh & 15;
  const int tid = threadIdx.x, w = tid >> 6, lane = tid & 63;
  const int l15 = lane & 15, g = lane >> 4;

  __shared__ __align__(16) unsigned short Kb[2][64 * 64];   // 16 KB
  __shared__ __align__(16) unsigned short Vb[2][64 * 64];   // 16 KB
  __shared__ __align__(16) unsigned short Pl[4][16 * 64];   //  8 KB -> 40960 total

  const int* __restrict__ maskp = mask + b * SLEN;

  const size_t head = (size_t)bh * SLEN;
  const int r8 = lane >> 3, c8 = lane & 7;
  const int swz = ((c8 ^ r8) * 16);
  const unsigned pswz = (unsigned)((l15 & 7) << 4);

  const int qbase = qt * 128 + w * 32;
  bf16x8 qf[2][2];
  {
    const unsigned short* qp0 = q_ws + (head + qbase + l15) * 64;
    const unsigned short* qp1 = q_ws + (head + qbase + 16 + l15) * 64;
    qf[0][0] = *(const bf16x8*)(qp0 + g * 8);
    qf[0][1] = *(const bf16x8*)(qp0 + 32 + g * 8);
    qf[1][0] = *(const bf16x8*)(qp1 + g * 8);
    qf[1][1] = *(const bf16x8*)(qp1 + 32 + g * 8);
  }

  auto stage = [&](int kt2, int bufi) {
#pragma unroll
    for (int cl = 0; cl < 2; ++cl) {
      const int rr = w * 16 + cl * 8 + r8;
      const char* gk = (const char*)(k_ws + (head + kt2 * 64 + rr) * 64) + swz;
      gload16(gk, &Kb[bufi][(w * 16 + cl * 8) * 64]);
      const char* gv = (const char*)(vT + ((size_t)(bh * 64 + rr)) * SLEN + kt2 * 64) + swz;
      gload16(gv, &Vb[bufi][(w * 16 + cl * 8) * 64]);
    }
  };

  stage(0, 0);
  __syncthreads();

  float m_run[2] = {-1e30f, -1e30f};
  float l_run[2] = {0.f, 0.f};
  f32x4 of[2][4];
#pragma unroll
  for (int qi = 0; qi < 2; ++qi)
#pragma unroll
    for (int n = 0; n < 4; ++n) of[qi][n] = zero4();

  unsigned short* Pw = (unsigned short*)Pl[w];
  int cur = 0;

  for (int kt = 0; kt < 32; ++kt) {
    const int kv0 = kt * 64;
    // mask bias for this tile: 4x int4 from L2-resident mask (no LDS)
    f32x4 mv[4];
#pragma unroll
    for (int s = 0; s < 4; ++s) {
      const int4 mm = *(const int4*)(maskp + kv0 + s * 16 + g * 4);
      mv[s][0] = mm.x ? 0.f : -1e9f;
      mv[s][1] = mm.y ? 0.f : -1e9f;
      mv[s][2] = mm.z ? 0.f : -1e9f;
      mv[s][3] = mm.w ? 0.f : -1e9f;
    }
    if (kt + 1 < 32) stage(kt + 1, cur ^ 1);
    const char* Kc = (const char*)Kb[cur];
    const char* Vc = (const char*)Vb[cur];

#pragma unroll
    for (int qi = 0; qi < 2; ++qi) {
      f32x4 sac[4];
      __builtin_amdgcn_s_setprio(1);
#pragma unroll
      for (int s = 0; s < 4; ++s) {
        const char* kr = Kc + (s * 16 + l15) * 128;
        const bf16x8 kf0 = *(const bf16x8*)(kr + ((unsigned)(g * 16) ^ pswz));
        const bf16x8 kf1 = *(const bf16x8*)(kr + ((unsigned)(64 + g * 16) ^ pswz));
        f32x4 zt = mv[s];
        zt = __builtin_amdgcn_mfma_f32_16x16x32_bf16(kf0, qf[qi][0], zt, 0, 0, 0);
        sac[s] = __builtin_amdgcn_mfma_f32_16x16x32_bf16(kf1, qf[qi][1], zt, 0, 0, 0);
      }
      __builtin_amdgcn_s_setprio(0);

      float tmax = -3.0e38f;
#pragma unroll
      for (int s = 0; s < 4; ++s)
#pragma unroll
        for (int rr = 0; rr < 4; ++rr) tmax = fmaxf(tmax, sac[s][rr]);
      tmax = fmaxf(tmax, __shfl_xor(tmax, 16));
      tmax = fmaxf(tmax, __shfl_xor(tmax, 32));
      if (!__all(tmax <= m_run[qi] + 8.f)) {
        const float mnew = fmaxf(m_run[qi], tmax);
        const float alpha = fexp2(m_run[qi] - mnew);
        float af[4];
#pragma unroll
        for (int rr = 0; rr < 4; ++rr) af[rr] = __shfl(alpha, g * 4 + rr);
#pragma unroll
        for (int n = 0; n < 4; ++n)
#pragma unroll
          for (int rr = 0; rr < 4; ++rr) of[qi][n][rr] *= af[rr];
        l_run[qi] *= alpha;
        m_run[qi] = mnew;
      }
      float psum = 0.f;
      unsigned pr[4][2];
#pragma unroll
      for (int s = 0; s < 4; ++s) {
        const float p0 = fexp2(sac[s][0] - m_run[qi]);
        const float p1 = fexp2(sac[s][1] - m_run[qi]);
        const float p2 = fexp2(sac[s][2] - m_run[qi]);
        const float p3 = fexp2(sac[s][3] - m_run[qi]);
        psum += (p0 + p1) + (p2 + p3);
        pr[s][0] = pk(p0, p1); pr[s][1] = pk(p2, p3);
      }
      l_run[qi] += psum;
#pragma unroll
      for (int s = 0; s < 4; ++s) {
        i32x2 wv; wv[0] = (int)pr[s][0]; wv[1] = (int)pr[s][1];
        *(i32x2*)(void*)((char*)Pw + l15 * 128 + ((unsigned)(s * 32 + g * 8) ^ pswz)) = wv;
      }

      __builtin_amdgcn_s_setprio(1);
#pragma unroll
      for (int k2 = 0; k2 < 2; ++k2) {
        const bf16x8 pa = *(const bf16x8*)(const void*)(
            (const char*)Pw + l15 * 128 + ((unsigned)(k2 * 64 + g * 16) ^ pswz));
#pragma unroll
        for (int n = 0; n < 4; ++n) {
          const bf16x8 vf = *(const bf16x8*)(
              Vc + (n * 16 + l15) * 128 + ((unsigned)(k2 * 64 + g * 16) ^ pswz));
          of[qi][n] = __builtin_amdgcn_mfma_f32_16x16x32_bf16(pa, vf, of[qi][n], 0, 0, 0);
        }
      }
      __builtin_amdgcn_s_setprio(0);
    }
    __syncthreads();
    cur ^= 1;
  }

#pragma unroll
  for (int qi = 0; qi < 2; ++qi) {
    float lt = l_run[qi];
    lt += __shfl_xor(lt, 16);
    lt += __shfl_xor(lt, 32);
    float inv[4];
#pragma unroll
    for (int rr = 0; rr < 4; ++rr) inv[rr] = 1.f / __shfl(lt, g * 4 + rr);
    const int qrow0 = qt * 128 + w * 32 + qi * 16;
#pragma unroll
    for (int n = 0; n < 4; ++n) {
      const int d = h * 64 + n * 16 + l15;
#pragma unroll
      for (int rr = 0; rr < 4; ++rr) {
        const int sr = qrow0 + 4 * g + rr;
        o_ws[((size_t)b * SLEN + sr) * DMODEL + d] = f2bf(of[qi][n][rr] * inv[rr]);
      }
    }
  }
}

// ---------------------------------------------------------------------------
// Output projection. DMA=1: A (o_ws bf16) + B (Wo_bf) both via gload16,
// linear LDS. DMA=0: reg-staged fallback.  (unchanged R9)
// ---------------------------------------------------------------------------
template <bool DMA>
__global__ __launch_bounds__(256)
void gemm_out_t(const unsigned short* __restrict__ ow,
                const unsigned short* __restrict__ wob,
                const float* __restrict__ Wo, const float* __restrict__ bo,
                float* __restrict__ out)
{
  const int bid = blockIdx.x;                      // 512 = 8 * 64
  const int wg = (bid & 7) * 64 + (bid >> 3);
  const int m0 = (wg >> 3) * 128;
  const int n0 = (wg & 7) * 128;

  const int tid = threadIdx.x;
  const int lane = tid & 63, wid = tid >> 6;
  const int l15 = lane & 15, g = lane >> 4;
  const int wr = wid >> 1, wc = wid & 1;

  __shared__ __align__(16) char LDS[32768];

  auto dmaA = [&](int kt2, int bufsel) {
    char* dst = LDS + bufsel * 8192;
#pragma unroll
    for (int q = 0; q < 2; ++q) {
      const int r0 = wid * 32 + q * 16;
      const unsigned short* src = ow + (size_t)(m0 + r0 + (lane >> 2)) * 1024
                                     + kt2 * 32 + (lane & 3) * 8;
      gload16(src, dst + r0 * 64);
    }
  };
  auto dmaB = [&](int kt2, int bufsel) {
    char* dst = LDS + 16384 + bufsel * 8192;
#pragma unroll
    for (int q = 0; q < 2; ++q) {
      const int r0 = wid * 32 + q * 16;
      const unsigned short* src = wob + (size_t)(n0 + r0 + (lane >> 2)) * 1024
                                      + kt2 * 32 + (lane & 3) * 8;
      gload16(src, dst + r0 * 64);
    }
  };

  const int srow = tid >> 1, sh = tid & 1;
  const unsigned short* __restrict__ Ag = ow + (size_t)(m0 + srow) * DMODEL + sh * 16;
  const float* __restrict__ Bg = Wo + (size_t)(n0 + srow) * DMODEL + sh * 16;
  const unsigned sw0 = (unsigned)(srow * 64) + (((unsigned)(sh * 2))     ^ ((unsigned)((srow >> 1) & 3))) * 16;
  const unsigned sw1 = (unsigned)(srow * 64) + (((unsigned)(sh * 2 + 1)) ^ ((unsigned)((srow >> 1) & 3))) * 16;
  i32x4 ar2[2];
  f32x4 br4[4];
  auto loadA = [&](int kt2) {
    const unsigned short* p = Ag + kt2 * 32;
    ar2[0] = *(const i32x4*)(p);
    ar2[1] = *(const i32x4*)(p + 8);
  };
  auto loadB = [&](int kt2) {
    const float* p = Bg + kt2 * 32;
#pragma unroll
    for (int j = 0; j < 4; ++j) br4[j] = *(const f32x4*)(p + j * 4);
  };
  auto packA = [&](int bufsel) {
    char* Ab = LDS + bufsel * 8192;
    *(i32x4*)(Ab + sw0) = ar2[0];
    *(i32x4*)(Ab + sw1) = ar2[1];
  };
  auto packB = [&](int bufsel) {
    char* Bb = LDS + 16384 + bufsel * 8192;
    i32x4 wv0, wv1;
    wv0[0] = (int)pk(br4[0][0], br4[0][1]); wv0[1] = (int)pk(br4[0][2], br4[0][3]);
    wv0[2] = (int)pk(br4[1][0], br4[1][1]); wv0[3] = (int)pk(br4[1][2], br4[1][3]);
    wv1[0] = (int)pk(br4[2][0], br4[2][1]); wv1[1] = (int)pk(br4[2][2], br4[2][3]);
    wv1[2] = (int)pk(br4[3][0], br4[3][1]); wv1[3] = (int)pk(br4[3][2], br4[3][3]);
    *(i32x4*)(Bb + sw0) = wv0;
    *(i32x4*)(Bb + sw1) = wv1;
  };

  f32x4 acc[4][4];
#pragma unroll
  for (int i = 0; i < 4; ++i)
#pragma unroll
    for (int j = 0; j < 4; ++j) acc[i][j] = zero4();

  if (DMA) {
    dmaA(0, 0); dmaB(0, 0);
  } else {
    loadA(0); loadB(0);
    packA(0); packB(0);
    loadA(1); loadB(1);
  }
  __syncthreads();

  for (int kt = 0; kt < 32; ++kt) {
    const int cur = kt & 1;
    if (kt + 1 < 32) {
      if (DMA) { dmaA(kt + 1, cur ^ 1); dmaB(kt + 1, cur ^ 1); }
      else     { packA(cur ^ 1); packB(cur ^ 1); }
    }
    if (!DMA && kt + 2 < 32) { loadA(kt + 2); loadB(kt + 2); }

    const char* Ab = LDS + cur * 8192;
    const char* Bb = LDS + 16384 + cur * 8192;
    bf16x8 afr[4], bfr[4];
#pragma unroll
    for (int i = 0; i < 4; ++i) {
      const int ra = wr * 64 + i * 16 + l15;
      const unsigned ab = DMA ? (unsigned)(g * 16)
                              : ((unsigned)(g ^ ((ra >> 1) & 3)) * 16);
      afr[i] = *(const bf16x8*)(Ab + ra * 64 + ab);
      const int rb = wc * 64 + i * 16 + l15;
      const unsigned bb2 = DMA ? (unsigned)(g * 16)
                               : ((unsigned)(g ^ ((rb >> 1) & 3)) * 16);
      bfr[i] = *(const bf16x8*)(Bb + rb * 64 + bb2);
    }
#pragma unroll
    for (int mi = 0; mi < 4; ++mi)
#pragma unroll
      for (int ni = 0; ni < 4; ++ni)
        acc[mi][ni] = __builtin_amdgcn_mfma_f32_16x16x32_bf16(
            afr[mi], bfr[ni], acc[mi][ni], 0, 0, 0);

    if (kt + 1 < 32) __syncthreads();
  }

  float bv4[4];
#pragma unroll
  for (int ni = 0; ni < 4; ++ni) bv4[ni] = bo[n0 + wc * 64 + ni * 16 + l15];
#pragma unroll
  for (int mi = 0; mi < 4; ++mi) {
#pragma unroll
    for (int ni = 0; ni < 4; ++ni) {
      const int n = n0 + wc * 64 + ni * 16 + l15;
#pragma unroll
      for (int rr = 0; rr < 4; ++rr) {
        const int m = m0 + wr * 64 + mi * 16 + 4 * g + rr;
        out[(size_t)m * DMODEL + n] = acc[mi][ni][rr] + bv4[ni];
      }
    }
  }
}

// ---------------------------------------------------------------------------
extern "C" void kernel_launch(void* const* d_in, const int* in_sizes, int n_in,
                              void* d_out, int out_size, void* d_ws, size_t ws_size,
                              hipStream_t stream) {
  const float* query = (const float*)d_in[0];
  const float* key_  = (const float*)d_in[1];
  const float* value = (const float*)d_in[2];
  const int*   mask  = (const int*)d_in[3];
  const float* Wq = (const float*)d_in[4];
  const float* bq = (const float*)d_in[5];
  const float* Wk = (const float*)d_in[6];
  const float* bk = (const float*)d_in[7];
  const float* Wv = (const float*)d_in[8];
  const float* bv = (const float*)d_in[9];
  const float* Wo = (const float*)d_in[10];
  const float* bo = (const float*)d_in[11];
  float* out = (float*)d_out;

  const size_t MiB = 1048576;
  char* ws = (char*)d_ws;
  unsigned short* q_ws = (unsigned short*)(ws);
  unsigned short* k_ws = (unsigned short*)(ws + 16 * MiB);
  unsigned short* vT   = (unsigned short*)(ws + 32 * MiB);
  unsigned short* o_ws = (unsigned short*)(ws + 48 * MiB);

  const bool big = ws_size >= 120 * MiB;
  unsigned short* xbf = big ? (unsigned short*)(ws + 64 * MiB) : (unsigned short*)0;
  unsigned short* wbf = big ? (unsigned short*)(ws + 112 * MiB)
                            : (unsigned short*)(ws + 48 * MiB);  // aliases o_ws (dead before attn)

  cvt_pre<<<dim3(2048), 256, 0, stream>>>(query, key_, value, Wq, Wk, Wv, Wo,
                                          xbf, wbf, big ? 1 : 0);
  if (big)
    gemm_qkv_t<true><<<dim3(1536), 256, 0, stream>>>(query, key_, value, xbf, wbf,
                                                     bq, bk, bv, q_ws, k_ws, vT);
  else
    gemm_qkv_t<false><<<dim3(1536), 256, 0, stream>>>(query, key_, value, xbf, wbf,
                                                      bq, bk, bv, q_ws, k_ws, vT);
  attn<<<dim3(64, 16), 256, 0, stream>>>(q_ws, k_ws, vT, mask, o_ws);
  if (big)
    gemm_out_t<true><<<dim3(512), 256, 0, stream>>>(o_ws, wbf + (size_t)3 * 1048576,
                                                    Wo, bo, out);
  else
    gemm_out_t<false><<<dim3(512), 256, 0, stream>>>(o_ws, (const unsigned short*)0,
                                                     Wo, bo, out);
}